// Round 12
// baseline (286.267 us; speedup 1.0000x reference)
//
#include <hip/hip_runtime.h>

#define T 4096
#define K 4096
#define O 4096
#define E 4
#define MAXT128 35

typedef __attribute__((ext_vector_type(8))) short bf16x8;
typedef __attribute__((ext_vector_type(4))) float f32x4;

__device__ __forceinline__ unsigned short f2bf(float f) {
  unsigned int u = __float_as_uint(f);
  u += 0x7fffu + ((u >> 16) & 1u);  // RNE
  return (unsigned short)(u >> 16);
}

// One block, 256 threads. perm; tile table (rowtile-major x 32 ntiles of 128);
// persistent 512-block schedule: seg0 = full 256x128 tile (XCD 4x8x16 region
// map), seg1 = at most one quarter-K (1024) subunit of a remainder tile.
__global__ void build_meta(const int* __restrict__ idx, int* __restrict__ perm,
                           int* __restrict__ meta, int4* __restrict__ t256,
                           int4* __restrict__ t128, int4* __restrict__ sched) {
  const int wave = threadIdx.x >> 6;
  const int lane = threadIdx.x & 63;
  __shared__ int s_off[E + 1];
  __shared__ int rtE[20], rtP[20], rtC[20];
  __shared__ int r_sh;
  int total = 0;
  for (int t0 = 0; t0 < T; t0 += 64)
    total += __popcll(__ballot(idx[t0 + lane] == wave));
  if (lane == 0) s_off[wave + 1] = total;
  __syncthreads();
  if (threadIdx.x == 0) {
    s_off[0] = 0;
    for (int e = 0; e < E; e++) s_off[e + 1] += s_off[e];
  }
  __syncthreads();
  int base = s_off[wave];
  const unsigned long long below = (1ull << lane) - 1ull;
  for (int t0 = 0; t0 < T; t0 += 64) {
    int e = idx[t0 + lane];
    unsigned long long m = __ballot(e == wave);
    if (e == wave) perm[base + __popcll(m & below)] = t0 + lane;
    base += __popcll(m);
  }
  if (threadIdx.x == 0) {
    int n = 0;
    for (int e = 0; e < E; e++) {
      int s = s_off[e], c = s_off[e + 1] - s;
      for (int ro = 0; ro < c; ro += 256) {
        rtE[n] = e; rtP[n] = s + ro; rtC[n] = (c - ro) < 256 ? (c - ro) : 256; n++;
      }
    }
    r_sh = n;
    meta[0] = n * 32;   // total 256x128 tiles
    int n1 = 0;
    for (int e = 0; e < E; e++) {
      int s = s_off[e], c = s_off[e + 1] - s;
      for (int ro = 0; ro < c; ro += 128)
        t128[n1++] = make_int4(e, s + ro, (c - ro) < 128 ? (c - ro) : 128, 0);
    }
    for (; n1 < MAXT128; n1++) t128[n1] = make_int4(-1, 0, 0, 0);
  }
  __syncthreads();
  const int r = r_sh;  // rowtiles, 16..19
  for (int i = threadIdx.x; i < 32 * r; i += 256)
    t256[i] = make_int4(rtE[i >> 5], rtP[i >> 5], rtC[i >> 5], (i & 31) * 128);
  for (int b = threadIdx.x; b < 512; b += 256) {
    const int ru = r - 16;  // 0..3
    // XCD region map: XCD owns 4 rowtiles x 16 ntiles (bijective over 512).
    const int xcd = b & 7, s = b >> 3;
    const int rt_ = 4 * (xcd >> 1) + (s >> 4);
    const int nt_ = 16 * (xcd & 1) + (s & 15);
    sched[b * 2 + 0] = make_int4(rt_ * 32 + nt_, 0, 128, 0);  // full: 128 ktiles(32)
    const int u0 = (b * ru) >> 2, u1 = ((b + 1) * ru) >> 2;
    if (u1 > u0) {
      const int u = u0;  // quarter-K subunit of remainder tile
      sched[b * 2 + 1] = make_int4(512 + (u >> 2), (u & 3) * 32, 32, 0);
    } else {
      sched[b * 2 + 1] = make_int4(-1, 0, 0, 0);
    }
  }
}

// Zero output regions of remainder tiles (atomic-combine targets).
// Grid 1536: 96 tiles x 16 row-groups of 16 rows x 128 cols.
__global__ void zero_rem(const int* __restrict__ meta, const int4* __restrict__ t256,
                         const int* __restrict__ perm, float* __restrict__ out) {
  const int tI = 512 + (int)blockIdx.x / 16;
  if (tI >= meta[0]) return;
  const int4 td = t256[tI];
  const int row = (blockIdx.x & 15) * 16 + ((int)threadIdx.x >> 4);
  if (row >= td.z) return;
  float4* p = (float4*)(out + (size_t)perm[td.y + row] * O + td.w) + (threadIdx.x & 15);
  const float4 z = {0.f, 0.f, 0.f, 0.f};
  p[0] = z; p[16] = z;
}

// Cast W (fp32->bf16) and gather-cast x rows into expert-sorted order.
__global__ void convert_kernel(const float4* __restrict__ w4, const float* __restrict__ x,
                               const int* __restrict__ perm,
                               ushort4* __restrict__ wb4, ushort4* __restrict__ xg4) {
  const size_t NW4 = (size_t)E * O * K / 4;
  const size_t NX4 = (size_t)T * K / 4;
  const size_t stride = (size_t)gridDim.x * blockDim.x;
  const size_t t0 = (size_t)blockIdx.x * blockDim.x + threadIdx.x;
  for (size_t i = t0; i < NW4; i += stride) {
    float4 v = w4[i];
    wb4[i] = make_ushort4(f2bf(v.x), f2bf(v.y), f2bf(v.z), f2bf(v.w));
  }
  for (size_t j = t0; j < NX4; j += stride) {
    int p = (int)(j >> 10);
    int c = (int)(j & 1023);
    float4 v = *((const float4*)(x + (size_t)perm[p] * K) + c);
    xg4[j] = make_ushort4(f2bf(v.x), f2bf(v.y), f2bf(v.z), f2bf(v.w));
  }
}

// -------- persistent 256x128 grouped GEMM, BK=32, 2 blocks/CU (TLP) --------
// 512 blocks (2/CU, 72KB LDS each), 8 waves (4M x 2N, per-wave 64x64 out).
// Triple-buffered 24KB buffers [A 16KB][B 8KB]; stage tile t+2 at top of
// region t; one {VM3; BAR} per 32-K tile. Swizzle: 2-row-block XOR on 16B
// slots (same as proven R7 formula). Co-resident block fills sync dead time.
__global__ __launch_bounds__(512, 4)
void gemm2(const unsigned short* __restrict__ xg, const unsigned short* __restrict__ wbb,
           const int* __restrict__ perm, const int4* __restrict__ t256,
           const int4* __restrict__ sched, float* __restrict__ out) {
  __shared__ unsigned short lds[36864];  // 72 KiB; buf i at i*12288 ushorts
  const int bid = blockIdx.x;
  const int tid = threadIdx.x;
  const int wid = tid >> 6, lane = tid & 63;
  const int wr = wid >> 1, wc = wid & 1;  // 4M x 2N waves
  const int kc4 = lane >> 4;

#define GLL(gp, lp) __builtin_amdgcn_global_load_lds( \
    (const __attribute__((address_space(1))) void*)(gp), \
    (__attribute__((address_space(3))) void*)(lp), 16, 0, 0)
// One K-tile stage: A slots [0,1024) via 2 issues, B slots [0,512) via 1.
#define STAGE(bo, ko) do { \
    GLL(srcA0 + (ko), &lds[(bo) + wid * 512]); \
    GLL(srcA1 + (ko), &lds[(bo) + 4096 + wid * 512]); \
    GLL(srcB0 + (ko), &lds[(bo) + 8192 + wid * 512]); \
  } while (0)
#define LOADA(bo) do { _Pragma("unroll") \
    for (int mi = 0; mi < 4; ++mi) \
      af[mi] = *(const bf16x8*)&lds[(bo) + aoff[mi]]; } while (0)
#define LOADB(bo) do { _Pragma("unroll") \
    for (int ni = 0; ni < 4; ++ni) \
      bf[ni] = *(const bf16x8*)&lds[(bo) + boff[ni]]; } while (0)
#define MFMA16() do { _Pragma("unroll") \
    for (int ni = 0; ni < 4; ++ni) _Pragma("unroll") \
      for (int mi = 0; mi < 4; ++mi) \
        acc[mi][ni] = __builtin_amdgcn_mfma_f32_16x16x32_bf16( \
            af[mi], bf[ni], acc[mi][ni], 0, 0, 0); } while (0)
#define BAR() do { __builtin_amdgcn_s_barrier(); asm volatile("" ::: "memory"); } while (0)
#define VM3() asm volatile("s_waitcnt vmcnt(3)" ::: "memory")
#define VM0() asm volatile("s_waitcnt vmcnt(0)" ::: "memory")
#define PRIO1() __builtin_amdgcn_s_setprio(1)
#define PRIO0() __builtin_amdgcn_s_setprio(0)

  // swizzled fragment offsets (ushort units); slot(r,c)=(r>>1)*8+((((r&1)<<2)|c)^((r>>1)&7))
  int aoff[4], boff[4];
#pragma unroll
  for (int mi = 0; mi < 4; ++mi) {
    int r = wr * 64 + mi * 16 + (lane & 15);
    aoff[mi] = (((r >> 1) << 3) + (((((r & 1) << 2) | kc4)) ^ ((r >> 1) & 7))) * 8;
  }
#pragma unroll
  for (int ni = 0; ni < 4; ++ni) {
    int r = wc * 64 + ni * 16 + (lane & 15);
    boff[ni] = 8192 + (((r >> 1) << 3) + (((((r & 1) << 2) | kc4)) ^ ((r >> 1) & 7))) * 8;
  }

  for (int sg = 0; sg < 2; ++sg) {
    const int4 sd = sched[bid * 2 + sg];
    if (sd.x < 0) break;
    const int4 td = t256[sd.x];
    const int e = td.x, p0 = td.y, rc = td.z, n0 = td.w;
    const int kt0 = sd.y;   // first 32-K tile
    const int nt = sd.z;    // 32-K tiles in segment (32 or 128)

    // staging source decode (slot -> row/c4, inverse of read swizzle)
    const unsigned short *srcA0, *srcA1, *srcB0;
    {
      int s0 = tid, s1 = 512 + tid;
      int b0 = s0 >> 3, v0 = (s0 & 7) ^ (b0 & 7);
      int r0 = b0 * 2 + (v0 >> 2), c0 = v0 & 3;
      int b1 = s1 >> 3, v1 = (s1 & 7) ^ (b1 & 7);
      int r1 = b1 * 2 + (v1 >> 2), c1 = v1 & 3;
      int ra0 = r0 < rc ? r0 : rc - 1;
      int ra1 = r1 < rc ? r1 : rc - 1;
      srcA0 = xg + (size_t)(p0 + ra0) * K + c0 * 8;
      srcA1 = xg + (size_t)(p0 + ra1) * K + c1 * 8;
      const unsigned short* wB = wbb + (size_t)e * O * K + (size_t)n0 * K;
      srcB0 = wB + (size_t)r0 * K + c0 * 8;   // rows 0..127 (slots 0..511)
    }

    f32x4 acc[4][4] = {};
    bf16x8 af[4], bf[4];

    const int kb = kt0 << 5;
    STAGE(0, kb);
    STAGE(12288, kb + 32);
    VM3(); BAR();

    int bc = 0, bn = 24576;
    for (int t = 0; t < nt; ++t) {
      const int tn = (t + 2 < nt ? t + 2 : nt - 1) + kt0;
      STAGE(bn, tn << 5);
      LOADA(bc); LOADB(bc);
      PRIO1(); MFMA16(); PRIO0();
      VM3(); BAR();
      bc = (bc == 24576) ? 0 : bc + 12288;
      bn = (bn == 24576) ? 0 : bn + 12288;
    }
    VM0();  // drain stale prefetch before epilogue / next segment

    // epilogue: C layout col=lane&15, row=(lane>>4)*4+reg
    if (sd.z == 128) {
#pragma unroll
      for (int mi = 0; mi < 4; ++mi) {
        const int rbase = wr * 64 + mi * 16 + (lane >> 4) * 4;
#pragma unroll
        for (int reg = 0; reg < 4; ++reg) {
          const int pr = rbase + reg;
          if (pr < rc) {
            float* orow = out + (size_t)perm[p0 + pr] * O + n0 + wc * 64 + (lane & 15);
#pragma unroll
            for (int ni = 0; ni < 4; ++ni) orow[ni * 16] = acc[mi][ni][reg];
          }
        }
      }
    } else {
#pragma unroll
      for (int mi = 0; mi < 4; ++mi) {
        const int rbase = wr * 64 + mi * 16 + (lane >> 4) * 4;
#pragma unroll
        for (int reg = 0; reg < 4; ++reg) {
          const int pr = rbase + reg;
          if (pr < rc) {
            float* orow = out + (size_t)perm[p0 + pr] * O + n0 + wc * 64 + (lane & 15);
#pragma unroll
            for (int ni = 0; ni < 4; ++ni)
              unsafeAtomicAdd(&orow[ni * 16], acc[mi][ni][reg]);
          }
        }
      }
    }
  }
}

// ---------------- fallback (small ws): 128x128 fp32-source reg-staged ----------------
__global__ __launch_bounds__(256)
void gemm_fb(const float* __restrict__ xf, const float* __restrict__ wf,
             const int* __restrict__ perm, const int4* __restrict__ tiles,
             float* __restrict__ out) {
  __shared__ unsigned short lds_a[128 * 64];
  __shared__ unsigned short lds_b[128 * 64];
  const int4 td = tiles[blockIdx.x];
  if (td.x < 0) return;
  const int e = td.x, p0 = td.y, rc = td.z;
  const int n0 = blockIdx.y * 128;
  const int wave = threadIdx.x >> 6, lane = threadIdx.x & 63;
  const int wr = wave >> 1, wc = wave & 1;
  f32x4 acc[4][4] = {};
  const float* wf_base = wf + (size_t)e * O * K + (size_t)n0 * K;
  for (int k0 = 0; k0 < K; k0 += 64) {
    if (k0) __syncthreads();
#pragma unroll
    for (int i = 0; i < 8; i++) {
      int l4 = i * 256 + (int)threadIdx.x;
      int row = l4 >> 4;
      int c4 = (l4 & 15) << 2;
      int ra = row < rc ? row : (rc - 1);
      const float4 va = *(const float4*)(xf + (size_t)perm[p0 + ra] * K + k0 + c4);
      *(ushort4*)&lds_a[row * 64 + c4] = make_ushort4(f2bf(va.x), f2bf(va.y), f2bf(va.z), f2bf(va.w));
      const float4 vb = *(const float4*)(wf_base + (size_t)row * K + k0 + c4);
      *(ushort4*)&lds_b[row * 64 + c4] = make_ushort4(f2bf(vb.x), f2bf(vb.y), f2bf(vb.z), f2bf(vb.w));
    }
    __syncthreads();
#pragma unroll
    for (int ks = 0; ks < 2; ks++) {
      bf16x8 a2[4], b2[4];
#pragma unroll
      for (int mi = 0; mi < 4; mi++)
        a2[mi] = *(const bf16x8*)&lds_a[(wr * 64 + mi * 16 + (lane & 15)) * 64 + ks * 32 + (lane >> 4) * 8];
#pragma unroll
      for (int ni = 0; ni < 4; ni++)
        b2[ni] = *(const bf16x8*)&lds_b[(wc * 64 + ni * 16 + (lane & 15)) * 64 + ks * 32 + (lane >> 4) * 8];
#pragma unroll
      for (int mi = 0; mi < 4; mi++)
#pragma unroll
        for (int ni = 0; ni < 4; ni++)
          acc[mi][ni] = __builtin_amdgcn_mfma_f32_16x16x32_bf16(a2[mi], b2[ni], acc[mi][ni], 0, 0, 0);
    }
  }
#pragma unroll
  for (int mi = 0; mi < 4; mi++) {
    const int rb = wr * 64 + mi * 16 + (lane >> 4) * 4;
#pragma unroll
    for (int reg = 0; reg < 4; reg++) {
      const int rt = rb + reg;
      if (rt < rc) {
        float* orow = out + (size_t)perm[p0 + rt] * O + n0 + wc * 64 + (lane & 15);
#pragma unroll
        for (int ni = 0; ni < 4; ni++) orow[ni * 16] = acc[mi][ni][reg];
      }
    }
  }
}

extern "C" void kernel_launch(void* const* d_in, const int* in_sizes, int n_in,
                              void* d_out, int out_size, void* d_ws, size_t ws_size,
                              hipStream_t stream) {
  const float* x = (const float*)d_in[0];
  const float* w = (const float*)d_in[1];
  const int* idx = (const int*)d_in[2];
  float* out = (float*)d_out;
  char* ws = (char*)d_ws;

  int* perm = (int*)ws;                        // 16 KB
  int* meta = (int*)(ws + 16384);              // 16 B
  int4* t256 = (int4*)(ws + 16640);            // 608*16 = 9728 B
  int4* t128 = (int4*)(ws + 26624);            // 560 B
  int4* sched = (int4*)(ws + 28672);           // 512*2*16 = 16 KB
  unsigned short* xg = (unsigned short*)(ws + 65536);          // 32 MB bf16
  unsigned short* wb = xg + (size_t)T * K;                     // 128 MB bf16
  const size_t need = 65536 + (size_t)T * K * 2 + (size_t)E * O * K * 2;

  build_meta<<<1, 256, 0, stream>>>(idx, perm, meta, t256, t128, sched);
  if (ws_size >= need) {
    zero_rem<<<1536, 256, 0, stream>>>(meta, t256, perm, out);
    convert_kernel<<<4096, 256, 0, stream>>>((const float4*)w, x, perm,
                                             (ushort4*)wb, (ushort4*)xg);
    gemm2<<<512, 512, 0, stream>>>(xg, wb, perm, t256, sched, out);
  } else {
    gemm_fb<<<dim3(MAXT128, 32), 256, 0, stream>>>(x, w, perm, t128, out);
  }
}